// Round 11
// baseline (280.441 us; speedup 1.0000x reference)
//
#include <hip/hip_runtime.h>
#include <cmath>

typedef unsigned short u16;
typedef unsigned int u32;
typedef __bf16 bf16x8 __attribute__((ext_vector_type(8)));
typedef float  floatx4 __attribute__((ext_vector_type(4)));
typedef float  floatx16 __attribute__((ext_vector_type(16)));
typedef unsigned int u32x4 __attribute__((ext_vector_type(4)));

#define T_DIM 2048
#define E_DIM 1024
#define H_DIM 16
#define HD    64
#define M_DIM 8192                    // B*T
#define NE    8388608                 // M*E  (also B*H*T*HD)
#define E2    1048576                 // E*E
#define QSCALE 0.18033688f            // 0.125 * log2(e): logits in exp2 domain

// float -> bf16 (RNE)
__device__ __forceinline__ u16 f2bf(float f) {
    unsigned u = __builtin_bit_cast(unsigned, f);
    return (u16)((u + 0x7FFFu + ((u >> 16) & 1u)) >> 16);
}
// two floats -> packed bf16x2
__device__ __forceinline__ u32 pack2bf(float f0, float f1) {
    u32 a0 = __builtin_bit_cast(u32, f0) + 0x8000u;
    u32 a1 = __builtin_bit_cast(u32, f1) + 0x8000u;
    return __builtin_amdgcn_perm(a1, a0, 0x07060302u);  // low16=bf(f0), high16=bf(f1)
}

// async global->LDS, 16B per lane. lds base wave-uniform; HW adds lane*16.
__device__ __forceinline__ void gl_lds16(const u16* g, const u16* l) {
    __builtin_amdgcn_global_load_lds(
        (const __attribute__((address_space(1))) void*)g,
        (__attribute__((address_space(3))) void*)l,
        16, 0, 0);
}

__device__ __forceinline__ bf16x8 ld_frag(const u16* p) {
    return *(const bf16x8*)p;
}

// ---------------------------------------------------------------------------
// x fp32 -> bf16, 8 elems/thread
// ---------------------------------------------------------------------------
__global__ void cvt_x_kernel(const float* __restrict__ x, u16* __restrict__ xb) {
    const size_t i = (size_t)blockIdx.x * 256 + threadIdx.x;
    const float4* s = (const float4*)x + i * 2;
    const float4 a = s[0], b = s[1];
    u16 v[8] __attribute__((aligned(16)));
    v[0]=f2bf(a.x); v[1]=f2bf(a.y); v[2]=f2bf(a.z); v[3]=f2bf(a.w);
    v[4]=f2bf(b.x); v[5]=f2bf(b.y); v[6]=f2bf(b.z); v[7]=f2bf(b.w);
    *(uint4*)(xb + i * 8) = *(const uint4*)v;
}

// ---------------------------------------------------------------------------
// W [K,N] fp32 -> Wt [N,K] bf16 (transpose+convert), 64x64 tiles.
// ---------------------------------------------------------------------------
__global__ void transpose_cvt_kernel(const float* __restrict__ w0, const float* __restrict__ w1,
                                     const float* __restrict__ w2, const float* __restrict__ w3,
                                     u16* __restrict__ out) {
    __shared__ u16 tile[64][65];
    const float* W = blockIdx.z == 0 ? w0 : blockIdx.z == 1 ? w1 : blockIdx.z == 2 ? w2 : w3;
    u16* O = out + (size_t)blockIdx.z * E2;
    const int k0 = blockIdx.y * 64, n0 = blockIdx.x * 64;
    const int r = threadIdx.x >> 2, cp = (threadIdx.x & 3) * 16;
    const float4* src = (const float4*)&W[(size_t)(k0 + r) * E_DIM + n0 + cp];
    #pragma unroll
    for (int j4 = 0; j4 < 4; ++j4) {
        const float4 f = src[j4];
        tile[r][cp + j4*4 + 0] = f2bf(f.x);
        tile[r][cp + j4*4 + 1] = f2bf(f.y);
        tile[r][cp + j4*4 + 2] = f2bf(f.z);
        tile[r][cp + j4*4 + 3] = f2bf(f.w);
    }
    __syncthreads();
    u16 vals[16] __attribute__((aligned(16)));
    #pragma unroll
    for (int j = 0; j < 16; ++j) vals[j] = tile[cp + j][r];
    u16* dst = &O[(size_t)(n0 + r) * E_DIM + k0 + cp];
    *(uint4*)dst       = *(const uint4*)vals;
    *(uint4*)(dst + 8) = *(const uint4*)(vals + 8);
}

// ---------------------------------------------------------------------------
// bf16 MFMA GEMM (m97 structure + LDS XOR swizzle, conflict-free).
// REMAP 0: fp32 out (out-proj).
// REMAP 1: bf16 head-split q/k (q gets QSCALE) + V^T direct to vt[bh][d][t].
// ---------------------------------------------------------------------------
template<int REMAP>
__global__ __launch_bounds__(256)
void gemm_bf16_kernel(const u16* __restrict__ A, const u16* __restrict__ Bt,
                      const float* __restrict__ bias0, const float* __restrict__ bias1,
                      const float* __restrict__ bias2, void* __restrict__ outp,
                      u16* __restrict__ vtp)
{
    __shared__ u16 As[128 * 32];
    __shared__ u16 Bs[128 * 32];
    const int tid = threadIdx.x;
    const int w = tid >> 6, lane = tid & 63, quad = lane >> 4, l15 = lane & 15;
    const int wm = w >> 1, wn = w & 1;
    const int r0 = blockIdx.y * 128, c0 = blockIdx.x * 128;

    floatx4 acc[4][4];
    #pragma unroll
    for (int mi = 0; mi < 4; ++mi)
        #pragma unroll
        for (int ni = 0; ni < 4; ++ni)
            acc[mi][ni] = (floatx4){0.f, 0.f, 0.f, 0.f};

    const int fsw = (quad ^ ((l15 >> 1) & 3)) * 8;   // swizzled frag chunk offset

    for (int k0 = 0; k0 < E_DIM; k0 += 32) {
        __syncthreads();
        #pragma unroll
        for (int i = 0; i < 2; ++i) {
            const int L = i * 256 + tid;               // 0..511
            const int row = L >> 2, s = L & 3;
            const int c = s ^ ((row >> 1) & 3);        // source chunk for this slot
            const unsigned off = __builtin_amdgcn_readfirstlane(i * 4096 + w * 1024);
            gl_lds16(&A [(size_t)(r0 + row) * E_DIM + k0 + c * 8], (u16*)((char*)As + off));
            gl_lds16(&Bt[(size_t)(c0 + row) * E_DIM + k0 + c * 8], (u16*)((char*)Bs + off));
        }
        __syncthreads();
        bf16x8 Af[4], Bf[4];
        #pragma unroll
        for (int mi = 0; mi < 4; ++mi) Af[mi] = ld_frag(&As[(wm*64 + mi*16 + l15) * 32 + fsw]);
        #pragma unroll
        for (int ni = 0; ni < 4; ++ni) Bf[ni] = ld_frag(&Bs[(wn*64 + ni*16 + l15) * 32 + fsw]);
        #pragma unroll
        for (int mi = 0; mi < 4; ++mi)
            #pragma unroll
            for (int ni = 0; ni < 4; ++ni)
                acc[mi][ni] = __builtin_amdgcn_mfma_f32_16x16x32_bf16(Af[mi], Bf[ni], acc[mi][ni], 0, 0, 0);
    }

    #pragma unroll
    for (int ni = 0; ni < 4; ++ni) {
        const int col = c0 + wn * 64 + ni * 16 + l15;
        float bv;
        int which = 0, cc = col;
        if (REMAP == 1) {
            which = col >> 10; cc = col & 1023;
            const float* bp_ = which == 0 ? bias0 : which == 1 ? bias1 : bias2;
            bv = bp_[cc];
        } else {
            bv = bias0[col];
        }
        #pragma unroll
        for (int mi = 0; mi < 4; ++mi) {
            if (REMAP == 1 && which == 2) {
                // V^T: vt[bh][d][t], 4 consecutive t -> one uint2 store
                const int h = cc >> 6, d = cc & 63;
                const int row0 = r0 + wm * 64 + mi * 16 + quad * 4;
                const int b = row0 >> 11, t0 = row0 & (T_DIM - 1);
                uint2 pk;
                pk.x = pack2bf(acc[mi][ni][0] + bv, acc[mi][ni][1] + bv);
                pk.y = pack2bf(acc[mi][ni][2] + bv, acc[mi][ni][3] + bv);
                *(uint2*)&vtp[((size_t)((b * H_DIM + h) * HD + d)) * T_DIM + t0] = pk;
            } else {
                #pragma unroll
                for (int r = 0; r < 4; ++r) {
                    const int row = r0 + wm * 64 + mi * 16 + quad * 4 + r;
                    float val = acc[mi][ni][r] + bv;
                    if (REMAP == 1) {
                        if (which == 0) val *= QSCALE;
                        const int h = cc >> 6, d = cc & 63;
                        const int b = row >> 11, t = row & (T_DIM - 1);
                        ((u16*)outp)[(size_t)which * NE +
                                     (((size_t)(b * H_DIM + h) * T_DIM + t) * HD + d)] = f2bf(val);
                    } else {
                        ((float*)outp)[(size_t)row * E_DIM + col] = val;
                    }
                }
            }
        }
    }
}

// C-layout packed pairs -> A-frag reg pairs via lane^32 exchange.
// VERIFIED path only (identical to v6's inline exchange; permlane variant
// removed after round-10 semantics bug).
__device__ __forceinline__ void xchg32(u32 ulo, u32 uhi, int hl, u32& rlo, u32& rhi) {
    const u32 rlo_x = __shfl_xor(ulo, 32, 64);
    const u32 rhi_x = __shfl_xor(uhi, 32, 64);
    rlo = hl ? rhi_x : ulo;
    rhi = hl ? uhi   : rlo_x;
}

// ---------------------------------------------------------------------------
// MFMA flash attention v7b: v6 (verified) + 64 queries/wave.
//  - Each wave owns 2 MFMA query-columns (64 q): every K/V fragment read
//    feeds 2x the MFMAs -> LDS fragment reads per FLOP halve.
//  - P C->A transform: verified shfl_xor exchange (same as v6).
//  - Max-free softmax, double-buffered K/V staging, XOR swizzles unchanged.
// Block = 256 queries; grid (bh, 8). Masks via wave-uniform rel per (kg,col).
// ---------------------------------------------------------------------------
__global__ __launch_bounds__(256, 2)
void attn_kernel(const u16* __restrict__ q, const u16* __restrict__ k,
                 const u16* __restrict__ vt, u16* __restrict__ y)
{
    __shared__ u16 Ks[2][128 * 64];   // [key][d], 8 chunks/row, XOR-swizzled
    __shared__ u16 Vs[2][64 * 128];   // [d][key], 16 chunks/row, swizzled

    const int tid = threadIdx.x;
    const int w = tid >> 6, lane = tid & 63;
    const int hl = lane >> 5, l31 = lane & 31, l7 = lane & 7;
    const int bh = blockIdx.x;                    // XCD = bh % 8
    const int qt = gridDim.y - 1 - blockIdx.y;    // heavy q-blocks dispatch first
    const int q0 = qt * 256;
    const int b = bh >> 4, h = bh & (H_DIM - 1);
    const size_t qkb = (size_t)bh * (T_DIM * HD);
    const size_t vtb = (size_t)bh * (HD * T_DIM);

    // Q as B-operand, 2 columns: query = qbase + c*32 + l31
    const int qbase = q0 + w * 64;
    bf16x8 Qf[2][4];
    #pragma unroll
    for (int c = 0; c < 2; ++c)
        #pragma unroll
        for (int kc = 0; kc < 4; ++kc)
            Qf[c][kc] = ld_frag(&q[qkb + (size_t)(qbase + c * 32 + l31) * HD + kc * 16 + hl * 8]);

    float rsum[2] = {0.f, 0.f};
    floatx16 O[2][2];
    #pragma unroll
    for (int i = 0; i < 16; ++i) {
        O[0][0][i] = 0.f; O[0][1][i] = 0.f; O[1][0][i] = 0.f; O[1][1][i] = 0.f;
    }

    auto stage = [&](int jt, int sel) {
        const int j0 = jt * 128;
        #pragma unroll
        for (int i = 0; i < 4; ++i) {
            const int L = i * 256 + tid;
            const unsigned off = __builtin_amdgcn_readfirstlane(i * 4096 + w * 1024);
            {   const int row = L >> 3, ch = (L & 7) ^ (row & 7);
                gl_lds16(&k[qkb + (size_t)(j0 + row) * HD + ch * 8],
                         (u16*)((char*)&Ks[sel][0] + off)); }
            {   const int row = L >> 4, ch = (L & 15) ^ (row & 7);
                gl_lds16(&vt[vtb + (size_t)row * T_DIM + j0 + ch * 8],
                         (u16*)((char*)&Vs[sel][0] + off)); }
        }
    };

    const int jt_max = 2 * qt + 1;
    stage(0, 0);
    for (int jt = 0; jt <= jt_max; ++jt) {
        __syncthreads();                       // drains stage(jt)
        if (jt < jt_max) stage(jt + 1, (jt + 1) & 1);
        const u16* const Kb = &Ks[jt & 1][0];
        const u16* const Vb = &Vs[jt & 1][0];

        const int dq = qbase - jt * 128;       // wave-uniform

        #pragma unroll
        for (int kg = 0; kg < 4; ++kg) {
            const int kstart = kg * 32;
            const int rel0 = dq - kstart;          // column 0
            const int rel1 = rel0 + 32;            // column 1
            const bool act0 = rel0 >= -31, act1 = rel1 >= -31;
            if (!act1) continue;                   // act1 implies widest coverage

            // shared K fragments for this key group
            bf16x8 Kf[4];
            const int krow = kstart + l31;
            #pragma unroll
            for (int kc = 0; kc < 4; ++kc)
                Kf[kc] = ld_frag(&Kb[krow * 64 + ((kc * 2 + hl) ^ l7) * 8]);

            bf16x8 Pf[2][2];
            #pragma unroll
            for (int c = 0; c < 2; ++c) {
                const bool act = c ? act1 : act0;
                if (!act) continue;
                const int rel = c ? rel1 : rel0;
                const bool bnd = rel < 31;

                floatx16 S;
                #pragma unroll
                for (int i = 0; i < 16; ++i) S[i] = 0.f;
                #pragma unroll
                for (int kc = 0; kc < 4; ++kc)
                    S = __builtin_amdgcn_mfma_f32_32x32x16_bf16(Kf[kc], Qf[c][kc], S, 0, 0, 0);

                u32 u[8];
                float rs = 0.f;
                #pragma unroll
                for (int i = 0; i < 8; ++i) {
                    const int row0 = (2*i & 3) + 8 * (i >> 1) + 4 * hl;
                    float p0 = __builtin_amdgcn_exp2f(S[2*i]);
                    float p1 = __builtin_amdgcn_exp2f(S[2*i + 1]);
                    if (bnd && (row0     > rel + l31)) p0 = 0.f;
                    if (bnd && (row0 + 1 > rel + l31)) p1 = 0.f;
                    rs += p0 + p1;
                    u[i] = pack2bf(p0, p1);
                }
                rsum[c] += rs;

                // C->A exchange: {reg0..3} per 16-key chunk
                u32 f0[4], f1[4];
                xchg32(u[0], u[2], hl, f0[0], f0[2]);
                xchg32(u[1], u[3], hl, f0[1], f0[3]);
                xchg32(u[4], u[6], hl, f1[0], f1[2]);
                xchg32(u[5], u[7], hl, f1[1], f1[3]);
                Pf[c][0] = __builtin_bit_cast(bf16x8, (u32x4){f0[0], f0[1], f0[2], f0[3]});
                Pf[c][1] = __builtin_bit_cast(bf16x8, (u32x4){f1[0], f1[1], f1[2], f1[3]});
            }

            // O += P @ V, V fragment shared by both columns
            #pragma unroll
            for (int c2 = 0; c2 < 2; ++c2) {
                const int kc16 = kg * 4 + c2 * 2 + hl;
                #pragma unroll
                for (int dh = 0; dh < 2; ++dh) {
                    const bf16x8 Vf = ld_frag(&Vb[(dh * 32 + l31) * 128 + (kc16 ^ l7) * 8]);
                    if (act0)
                        O[0][dh] = __builtin_amdgcn_mfma_f32_32x32x16_bf16(Pf[0][c2], Vf, O[0][dh], 0, 0, 0);
                    O[1][dh] = __builtin_amdgcn_mfma_f32_32x32x16_bf16(Pf[1][c2], Vf, O[1][dh], 0, 0, 0);
                }
            }
        }
    }

    // epilogue: reduce halves, normalize, store merged heads
    #pragma unroll
    for (int c = 0; c < 2; ++c) {
        float rs = rsum[c];
        rs += __shfl_xor(rs, 32, 64);
        const float linv = 1.0f / rs;          // for query qbase + c*32 + l31
        #pragma unroll
        for (int i = 0; i < 16; ++i) {
            const int qr = (i & 3) + 8 * (i >> 2) + 4 * hl;    // query row of reg i
            const float lq = __shfl(linv, qr, 32);
            const int t = qbase + c * 32 + qr;
            const size_t base = ((size_t)(b * T_DIM + t)) * E_DIM + h * HD;
            y[base + l31]      = f2bf(O[c][0][i] * lq);
            y[base + 32 + l31] = f2bf(O[c][1][i] * lq);
        }
    }
}

extern "C" void kernel_launch(void* const* d_in, const int* in_sizes, int n_in,
                              void* d_out, int out_size, void* d_ws, size_t ws_size,
                              hipStream_t stream)
{
    const float* x  = (const float*)d_in[0];
    const float* Wq = (const float*)d_in[2];
    const float* bq = (const float*)d_in[3];
    const float* Wk = (const float*)d_in[4];
    const float* bk = (const float*)d_in[5];
    const float* Wv = (const float*)d_in[6];
    const float* bv = (const float*)d_in[7];
    const float* Wp = (const float*)d_in[8];
    const float* bp = (const float*)d_in[9];

    u16* xb  = (u16*)d_ws;          // NE
    u16* wt  = xb + NE;             // 4*E2
    u16* qb  = wt + 4 * (size_t)E2; // NE (q)
    u16* kb  = qb + NE;             // NE (k)
    u16* vtb = kb + NE;             // NE (V^T, written by the QKV GEMM)
    u16* yb  = vtb + NE;            // NE

    cvt_x_kernel<<<NE / (256 * 8), 256, 0, stream>>>(x, xb);
    transpose_cvt_kernel<<<dim3(16, 16, 4), 256, 0, stream>>>(Wq, Wk, Wv, Wp, wt);
    gemm_bf16_kernel<1><<<dim3(24, 64), 256, 0, stream>>>(xb, wt, bq, bk, bv, qb, vtb);
    attn_kernel<<<dim3(64, 8), 256, 0, stream>>>(qb, kb, vtb, yb);
    gemm_bf16_kernel<0><<<dim3(8, 64), 256, 0, stream>>>(yb, wt + 3 * (size_t)E2, bp, bp, bp, (float*)d_out, nullptr);
}

// Round 12
// 255.158 us; speedup vs baseline: 1.0991x; 1.0991x over previous
//
#include <hip/hip_runtime.h>
#include <cmath>

typedef unsigned short u16;
typedef unsigned int u32;
typedef __bf16 bf16x8 __attribute__((ext_vector_type(8)));
typedef float  floatx4 __attribute__((ext_vector_type(4)));
typedef float  floatx16 __attribute__((ext_vector_type(16)));
typedef unsigned int u32x4 __attribute__((ext_vector_type(4)));

#define T_DIM 2048
#define E_DIM 1024
#define H_DIM 16
#define HD    64
#define M_DIM 8192                    // B*T
#define NE    8388608                 // M*E  (also B*H*T*HD)
#define E2    1048576                 // E*E
#define QSCALE 0.18033688f            // 0.125 * log2(e): logits in exp2 domain

// float -> bf16 (RNE)
__device__ __forceinline__ u16 f2bf(float f) {
    unsigned u = __builtin_bit_cast(unsigned, f);
    return (u16)((u + 0x7FFFu + ((u >> 16) & 1u)) >> 16);
}
// two floats -> packed bf16x2
__device__ __forceinline__ u32 pack2bf(float f0, float f1) {
    u32 a0 = __builtin_bit_cast(u32, f0) + 0x8000u;
    u32 a1 = __builtin_bit_cast(u32, f1) + 0x8000u;
    return __builtin_amdgcn_perm(a1, a0, 0x07060302u);  // low16=bf(f0), high16=bf(f1)
}

// async global->LDS, 16B per lane. lds base wave-uniform; HW adds lane*16.
__device__ __forceinline__ void gl_lds16(const u16* g, const u16* l) {
    __builtin_amdgcn_global_load_lds(
        (const __attribute__((address_space(1))) void*)g,
        (__attribute__((address_space(3))) void*)l,
        16, 0, 0);
}

__device__ __forceinline__ bf16x8 ld_frag(const u16* p) {
    return *(const bf16x8*)p;
}

// ---------------------------------------------------------------------------
// x fp32 -> bf16, 8 elems/thread
// ---------------------------------------------------------------------------
__global__ void cvt_x_kernel(const float* __restrict__ x, u16* __restrict__ xb) {
    const size_t i = (size_t)blockIdx.x * 256 + threadIdx.x;
    const float4* s = (const float4*)x + i * 2;
    const float4 a = s[0], b = s[1];
    u16 v[8] __attribute__((aligned(16)));
    v[0]=f2bf(a.x); v[1]=f2bf(a.y); v[2]=f2bf(a.z); v[3]=f2bf(a.w);
    v[4]=f2bf(b.x); v[5]=f2bf(b.y); v[6]=f2bf(b.z); v[7]=f2bf(b.w);
    *(uint4*)(xb + i * 8) = *(const uint4*)v;
}

// ---------------------------------------------------------------------------
// W [K,N] fp32 -> Wt [N,K] bf16 (transpose+convert), 64x64 tiles.
// ---------------------------------------------------------------------------
__global__ void transpose_cvt_kernel(const float* __restrict__ w0, const float* __restrict__ w1,
                                     const float* __restrict__ w2, const float* __restrict__ w3,
                                     u16* __restrict__ out) {
    __shared__ u16 tile[64][65];
    const float* W = blockIdx.z == 0 ? w0 : blockIdx.z == 1 ? w1 : blockIdx.z == 2 ? w2 : w3;
    u16* O = out + (size_t)blockIdx.z * E2;
    const int k0 = blockIdx.y * 64, n0 = blockIdx.x * 64;
    const int r = threadIdx.x >> 2, cp = (threadIdx.x & 3) * 16;
    const float4* src = (const float4*)&W[(size_t)(k0 + r) * E_DIM + n0 + cp];
    #pragma unroll
    for (int j4 = 0; j4 < 4; ++j4) {
        const float4 f = src[j4];
        tile[r][cp + j4*4 + 0] = f2bf(f.x);
        tile[r][cp + j4*4 + 1] = f2bf(f.y);
        tile[r][cp + j4*4 + 2] = f2bf(f.z);
        tile[r][cp + j4*4 + 3] = f2bf(f.w);
    }
    __syncthreads();
    u16 vals[16] __attribute__((aligned(16)));
    #pragma unroll
    for (int j = 0; j < 16; ++j) vals[j] = tile[cp + j][r];
    u16* dst = &O[(size_t)(n0 + r) * E_DIM + k0 + cp];
    *(uint4*)dst       = *(const uint4*)vals;
    *(uint4*)(dst + 8) = *(const uint4*)(vals + 8);
}

// ---------------------------------------------------------------------------
// bf16 MFMA GEMM (m97 structure + LDS XOR swizzle, conflict-free).
// REMAP 0: fp32 out (out-proj).
// REMAP 1: bf16 head-split q/k (q gets QSCALE) + V^T direct to vt[bh][d][t].
// ---------------------------------------------------------------------------
template<int REMAP>
__global__ __launch_bounds__(256)
void gemm_bf16_kernel(const u16* __restrict__ A, const u16* __restrict__ Bt,
                      const float* __restrict__ bias0, const float* __restrict__ bias1,
                      const float* __restrict__ bias2, void* __restrict__ outp,
                      u16* __restrict__ vtp)
{
    __shared__ u16 As[128 * 32];
    __shared__ u16 Bs[128 * 32];
    const int tid = threadIdx.x;
    const int w = tid >> 6, lane = tid & 63, quad = lane >> 4, l15 = lane & 15;
    const int wm = w >> 1, wn = w & 1;
    const int r0 = blockIdx.y * 128, c0 = blockIdx.x * 128;

    floatx4 acc[4][4];
    #pragma unroll
    for (int mi = 0; mi < 4; ++mi)
        #pragma unroll
        for (int ni = 0; ni < 4; ++ni)
            acc[mi][ni] = (floatx4){0.f, 0.f, 0.f, 0.f};

    const int fsw = (quad ^ ((l15 >> 1) & 3)) * 8;   // swizzled frag chunk offset

    for (int k0 = 0; k0 < E_DIM; k0 += 32) {
        __syncthreads();
        #pragma unroll
        for (int i = 0; i < 2; ++i) {
            const int L = i * 256 + tid;               // 0..511
            const int row = L >> 2, s = L & 3;
            const int c = s ^ ((row >> 1) & 3);        // source chunk for this slot
            const unsigned off = __builtin_amdgcn_readfirstlane(i * 4096 + w * 1024);
            gl_lds16(&A [(size_t)(r0 + row) * E_DIM + k0 + c * 8], (u16*)((char*)As + off));
            gl_lds16(&Bt[(size_t)(c0 + row) * E_DIM + k0 + c * 8], (u16*)((char*)Bs + off));
        }
        __syncthreads();
        bf16x8 Af[4], Bf[4];
        #pragma unroll
        for (int mi = 0; mi < 4; ++mi) Af[mi] = ld_frag(&As[(wm*64 + mi*16 + l15) * 32 + fsw]);
        #pragma unroll
        for (int ni = 0; ni < 4; ++ni) Bf[ni] = ld_frag(&Bs[(wn*64 + ni*16 + l15) * 32 + fsw]);
        #pragma unroll
        for (int mi = 0; mi < 4; ++mi)
            #pragma unroll
            for (int ni = 0; ni < 4; ++ni)
                acc[mi][ni] = __builtin_amdgcn_mfma_f32_16x16x32_bf16(Af[mi], Bf[ni], acc[mi][ni], 0, 0, 0);
    }

    #pragma unroll
    for (int ni = 0; ni < 4; ++ni) {
        const int col = c0 + wn * 64 + ni * 16 + l15;
        float bv;
        int which = 0, cc = col;
        if (REMAP == 1) {
            which = col >> 10; cc = col & 1023;
            const float* bp_ = which == 0 ? bias0 : which == 1 ? bias1 : bias2;
            bv = bp_[cc];
        } else {
            bv = bias0[col];
        }
        #pragma unroll
        for (int mi = 0; mi < 4; ++mi) {
            if (REMAP == 1 && which == 2) {
                // V^T: vt[bh][d][t], 4 consecutive t -> one uint2 store
                const int h = cc >> 6, d = cc & 63;
                const int row0 = r0 + wm * 64 + mi * 16 + quad * 4;
                const int b = row0 >> 11, t0 = row0 & (T_DIM - 1);
                uint2 pk;
                pk.x = pack2bf(acc[mi][ni][0] + bv, acc[mi][ni][1] + bv);
                pk.y = pack2bf(acc[mi][ni][2] + bv, acc[mi][ni][3] + bv);
                *(uint2*)&vtp[((size_t)((b * H_DIM + h) * HD + d)) * T_DIM + t0] = pk;
            } else {
                #pragma unroll
                for (int r = 0; r < 4; ++r) {
                    const int row = r0 + wm * 64 + mi * 16 + quad * 4 + r;
                    float val = acc[mi][ni][r] + bv;
                    if (REMAP == 1) {
                        if (which == 0) val *= QSCALE;
                        const int h = cc >> 6, d = cc & 63;
                        const int b = row >> 11, t = row & (T_DIM - 1);
                        ((u16*)outp)[(size_t)which * NE +
                                     (((size_t)(b * H_DIM + h) * T_DIM + t) * HD + d)] = f2bf(val);
                    } else {
                        ((float*)outp)[(size_t)row * E_DIM + col] = val;
                    }
                }
            }
        }
    }
}

// C-layout packed pairs -> A-frag reg pairs via lane^32 exchange (verified).
__device__ __forceinline__ void xchg32(u32 ulo, u32 uhi, int hl, u32& rlo, u32& rhi) {
    const u32 rlo_x = __shfl_xor(ulo, 32, 64);
    const u32 rhi_x = __shfl_xor(uhi, 32, 64);
    rlo = hl ? rhi_x : ulo;
    rhi = hl ? uhi   : rlo_x;
}

// ---------------------------------------------------------------------------
// MFMA flash attention v8 = v6 (verified round 8) + complementary q-tile
// pairing. Each block processes strip tq = 15-y then tq = y: exactly
// (16-y)+(y+1) = 17 tile-visits per block -> perfectly uniform load, no
// causal tail. Grid (64 bh, 8). Compute body (masks, swizzles, exchange,
// double-buffered staging) verbatim v6; only the outer strip loop and a
// WAR barrier before each strip's first stage are new.
// ---------------------------------------------------------------------------
__global__ __launch_bounds__(256, 2)
void attn_kernel(const u16* __restrict__ q, const u16* __restrict__ k,
                 const u16* __restrict__ vt, u16* __restrict__ y)
{
    __shared__ u16 Ks[2][128 * 64];   // [key][d], 8 chunks/row, XOR-swizzled
    __shared__ u16 Vs[2][64 * 128];   // [d][key], 16 chunks/row, swizzled

    const int tid = threadIdx.x;
    const int w = tid >> 6, lane = tid & 63;
    const int hl = lane >> 5, l31 = lane & 31, l7 = lane & 7;
    const int bh = blockIdx.x;                    // XCD = bh % 8
    const int b = bh >> 4, h = bh & (H_DIM - 1);
    const size_t qkb = (size_t)bh * (T_DIM * HD);
    const size_t vtb = (size_t)bh * (HD * T_DIM);

    auto stage = [&](int jt, int sel) {
        const int j0 = jt * 128;
        #pragma unroll
        for (int i = 0; i < 4; ++i) {
            const int L = i * 256 + tid;
            const unsigned off = __builtin_amdgcn_readfirstlane(i * 4096 + w * 1024);
            {   const int row = L >> 3, ch = (L & 7) ^ (row & 7);
                gl_lds16(&k[qkb + (size_t)(j0 + row) * HD + ch * 8],
                         (u16*)((char*)&Ks[sel][0] + off)); }
            {   const int row = L >> 4, ch = (L & 15) ^ (row & 7);
                gl_lds16(&vt[vtb + (size_t)row * T_DIM + j0 + ch * 8],
                         (u16*)((char*)&Vs[sel][0] + off)); }
        }
    };

    #pragma unroll 1
    for (int s = 0; s < 2; ++s) {
        const int tq = s ? blockIdx.y : (15 - blockIdx.y);   // paired strips: 17 tiles total
        const int q0 = tq * 128;

        // Q as B-operand: lane holds Q[d = kc*16 + hl*8 + j][query = q0+w*32+l31]
        const int qrow = q0 + w * 32 + l31;
        bf16x8 Qf[4];
        #pragma unroll
        for (int kc = 0; kc < 4; ++kc)
            Qf[kc] = ld_frag(&q[qkb + (size_t)qrow * HD + kc * 16 + hl * 8]);

        float rsum = 0.f;
        floatx16 O[2];
        #pragma unroll
        for (int i = 0; i < 16; ++i) { O[0][i] = 0.f; O[1][i] = 0.f; }

        __syncthreads();                  // WAR: prior strip's LDS reads drained
        stage(0, 0);
        for (int jt = 0; jt <= tq; ++jt) {
            __syncthreads();              // drains stage(jt)
            if (jt < tq) stage(jt + 1, (jt + 1) & 1);
            const u16* const Kb = &Ks[jt & 1][0];
            const u16* const Vb = &Vs[jt & 1][0];

            const bool diag = (jt == tq);
            const int nkg = diag ? (w + 1) : 4;    // active 32-key groups

            #pragma unroll
            for (int kg = 0; kg < 4; ++kg) {
                if (kg < nkg) {
                    // S^T = K_kg @ Q : D[key=(reg&3)+8*(reg>>2)+4*hl][query=l31]
                    floatx16 S;
                    #pragma unroll
                    for (int i = 0; i < 16; ++i) S[i] = 0.f;
                    const int krow = kg * 32 + l31;
                    #pragma unroll
                    for (int kc = 0; kc < 4; ++kc) {
                        const int ch = (kc * 2 + hl) ^ l7;      // krow&7 == l7
                        S = __builtin_amdgcn_mfma_f32_32x32x16_bf16(
                                ld_frag(&Kb[krow * 64 + ch * 8]), Qf[kc], S, 0, 0, 0);
                    }

                    // exp2 (+ causal mask on boundary group), rsum, pack
                    const bool bnd = diag && (kg == w);
                    u32 u[8];
                    #pragma unroll
                    for (int i = 0; i < 8; ++i) {
                        const int row0 = (2*i & 3) + 8 * (i >> 1) + 4 * hl;
                        float p0 = __builtin_amdgcn_exp2f(S[2*i]);
                        float p1 = __builtin_amdgcn_exp2f(S[2*i + 1]);
                        if (bnd && (row0     > l31)) p0 = 0.f;
                        if (bnd && (row0 + 1 > l31)) p1 = 0.f;
                        rsum += p0 + p1;
                        u[i] = pack2bf(p0, p1);
                    }
                    // lane^32 exchange: build PV A-frags (m=query=l31, k=keys)
                    u32 f0[4], f1[4];
                    xchg32(u[0], u[2], hl, f0[0], f0[2]);
                    xchg32(u[1], u[3], hl, f0[1], f0[3]);
                    xchg32(u[4], u[6], hl, f1[0], f1[2]);
                    xchg32(u[5], u[7], hl, f1[1], f1[3]);

                    // O[dh] += P_chunk @ V
                    #pragma unroll
                    for (int c2 = 0; c2 < 2; ++c2) {
                        const bf16x8 Pf = __builtin_bit_cast(bf16x8,
                            c2 ? (u32x4){f1[0], f1[1], f1[2], f1[3]}
                               : (u32x4){f0[0], f0[1], f0[2], f0[3]});
                        const int kc16 = kg * 4 + c2 * 2 + hl;
                        #pragma unroll
                        for (int dh = 0; dh < 2; ++dh) {
                            const int d = dh * 32 + l31;
                            const int ch = kc16 ^ l7;           // d&7 == l7
                            O[dh] = __builtin_amdgcn_mfma_f32_32x32x16_bf16(
                                        Pf, ld_frag(&Vb[d * 128 + ch * 8]), O[dh], 0, 0, 0);
                        }
                    }
                }
            }
        }

        // epilogue: complete row sums (halves), normalize, store merged heads
        rsum += __shfl_xor(rsum, 32, 64);
        const float linv = 1.0f / rsum;            // for query l31
        #pragma unroll
        for (int i = 0; i < 16; ++i) {
            const int qr = (i & 3) + 8 * (i >> 2) + 4 * hl;    // query row of reg i
            const float lq = __shfl(linv, qr, 32);
            const int t = q0 + w * 32 + qr;
            const size_t base = ((size_t)(b * T_DIM + t)) * E_DIM + h * HD;
            y[base + l31]      = f2bf(O[0][i] * lq);
            y[base + 32 + l31] = f2bf(O[1][i] * lq);
        }
    }
}

extern "C" void kernel_launch(void* const* d_in, const int* in_sizes, int n_in,
                              void* d_out, int out_size, void* d_ws, size_t ws_size,
                              hipStream_t stream)
{
    const float* x  = (const float*)d_in[0];
    const float* Wq = (const float*)d_in[2];
    const float* bq = (const float*)d_in[3];
    const float* Wk = (const float*)d_in[4];
    const float* bk = (const float*)d_in[5];
    const float* Wv = (const float*)d_in[6];
    const float* bv = (const float*)d_in[7];
    const float* Wp = (const float*)d_in[8];
    const float* bp = (const float*)d_in[9];

    u16* xb  = (u16*)d_ws;          // NE
    u16* wt  = xb + NE;             // 4*E2
    u16* qb  = wt + 4 * (size_t)E2; // NE (q)
    u16* kb  = qb + NE;             // NE (k)
    u16* vtb = kb + NE;             // NE (V^T, written by the QKV GEMM)
    u16* yb  = vtb + NE;            // NE

    cvt_x_kernel<<<NE / (256 * 8), 256, 0, stream>>>(x, xb);
    transpose_cvt_kernel<<<dim3(16, 16, 4), 256, 0, stream>>>(Wq, Wk, Wv, Wp, wt);
    gemm_bf16_kernel<1><<<dim3(24, 64), 256, 0, stream>>>(xb, wt, bq, bk, bv, qb, vtb);
    attn_kernel<<<dim3(64, 8), 256, 0, stream>>>(qb, kb, vtb, yb);
    gemm_bf16_kernel<0><<<dim3(8, 64), 256, 0, stream>>>(yb, wt + 3 * (size_t)E2, bp, bp, bp, (float*)d_out, nullptr);
}